// Round 6
// baseline (383.063 us; speedup 1.0000x reference)
//
#include <hip/hip_runtime.h>
#include <stdint.h>

// GAT forward, MI355X. FP32 in/out; edge_index int32. N=50000, E=800000,
// HEADS=4, C=64 (HC=256).
// Pipeline:
//   prep:  us/ud[4][256] = W @ att (fp32-exact logits path)
//   trans: Wth/Wtl[n][k] = trunc-split bf16 of W^T (L2-resident B for GEMM)
//   att:   a_src/a_dst[i][h] = x[i]·us/ud  (fp32 exact)
//   gemm:  H = x@W via split-bf16 MFMA (3 terms, err ~2^-17), H stored bf16.
//          R6: 32-row x 256-col blocks (1563), wave = 32x64 tile, explicit
//          2-stage load pipeline (R5 was latency-bound: MfmaUtil 8.5%).
//   hist/scanA+B+C/scatter: CSR of edges grouped by destination (src idx only)
//   gather: out = (w_self*h_i + sum_j w_j*h_j)/(sum w) + bias, PReLU
//           w computed inline from a_src[j]+a_dst[i] (leaky+exp), unroll x4.
// Softmax shift omitted: logits fp32-exact, |e|<~12 -> exp<=1.6e5, fp32-safe;
// softmax is shift-invariant. Dominant output error = bf16 H storage (~0.016
// absmax vs 0.0575 threshold, verified rounds 3/5).

using u16 = unsigned short;
typedef float f32x4 __attribute__((ext_vector_type(4)));
typedef __bf16 bf16x8 __attribute__((ext_vector_type(8)));
typedef u16 u16x8 __attribute__((ext_vector_type(8)));

#define NEG 0.2f

__device__ __forceinline__ float bf2f(u16 u) {
    union { uint32_t i; float f; } v; v.i = ((uint32_t)u) << 16; return v.f;
}
__device__ __forceinline__ u16 f2bf(float f) {          // RNE
    union { float f; uint32_t i; } v; v.f = f;
    uint32_t r = v.i + 0x7FFFu + ((v.i >> 16) & 1u);
    return (u16)(r >> 16);
}
// trunc split: f ~= hi + lo with |err| ~ 2^-17 |f|
__device__ __forceinline__ void split2(float f, u16& h, u16& l) {
    union { float f; uint32_t i; } v; v.f = f;
    h = (u16)(v.i >> 16);
    float r = f - bf2f(h);
    union { float f; uint32_t i; } w; w.f = r;
    l = (u16)(w.i >> 16);
}
__device__ __forceinline__ float wexp(float e) {
    e = e >= 0.f ? e : NEG * e;
    return __expf(e);
}

// ---------------- prep: us[h][k] = sum_c W[k][h*64+c]*attS[h][c] -----------
__global__ __launch_bounds__(256) void prep_kernel(
    const float* __restrict__ W, const float* __restrict__ attS,
    const float* __restrict__ attD, float* __restrict__ us, float* __restrict__ ud)
{
    const int k = threadIdx.x;
#pragma unroll
    for (int hh = 0; hh < 4; hh++) {
        float ss = 0.f, sd = 0.f;
        for (int c = 0; c < 64; c++) {
            float w = W[k * 256 + hh * 64 + c];
            ss += w * attS[hh * 64 + c];
            sd += w * attD[hh * 64 + c];
        }
        us[hh * 256 + k] = ss;
        ud[hh * 256 + k] = sd;
    }
}

// ---------------- trans: Wth/Wtl[n*256+k] = split(W[k*256+n]) --------------
__global__ __launch_bounds__(256) void trans_kernel(
    const float* __restrict__ W, u16* __restrict__ Wth, u16* __restrict__ Wtl)
{
    const int k = blockIdx.x, n = threadIdx.x;      // coalesced read along n
    u16 h, l;
    split2(W[k * 256 + n], h, l);
    Wth[n * 256 + k] = h;
    Wtl[n * 256 + k] = l;
}

// ---------------- att: a_src[i][h] = x[i]·us[h] (fp32 exact) ---------------
__global__ __launch_bounds__(256) void att_kernel(
    const float* __restrict__ X, const float* __restrict__ usg,
    const float* __restrict__ udg, float* __restrict__ a_src,
    float* __restrict__ a_dst, int Nn)
{
    __shared__ float us[1024], ud[1024];
    const int tid = threadIdx.x;
#pragma unroll
    for (int i = 0; i < 4; i++) {
        us[i * 256 + tid] = usg[i * 256 + tid];
        ud[i * 256 + tid] = udg[i * 256 + tid];
    }
    __syncthreads();
    const int wave = tid >> 6, lane = tid & 63;
    const int node = blockIdx.x * 4 + wave;
    if (node >= Nn) return;
    const float4 xv = *(const float4*)(X + (size_t)node * 256 + lane * 4);
    float ps[4], pd[4];
#pragma unroll
    for (int hh = 0; hh < 4; hh++) {
        int b = hh * 256 + lane * 4;
        ps[hh] = xv.x * us[b] + xv.y * us[b + 1] + xv.z * us[b + 2] + xv.w * us[b + 3];
        pd[hh] = xv.x * ud[b] + xv.y * ud[b + 1] + xv.z * ud[b + 2] + xv.w * ud[b + 3];
    }
#pragma unroll
    for (int off = 32; off > 0; off >>= 1)
#pragma unroll
        for (int hh = 0; hh < 4; hh++) {
            ps[hh] += __shfl_down(ps[hh], off, 64);
            pd[hh] += __shfl_down(pd[hh], off, 64);
        }
    if (lane == 0)
#pragma unroll
        for (int hh = 0; hh < 4; hh++) {
            a_src[node * 4 + hh] = ps[hh];
            a_dst[node * 4 + hh] = pd[hh];
        }
}

// ---------------- GEMM: H = x @ W, LDS-free, split-bf16, pipelined ---------
// 32-row x 256-col block (4 waves; wave w owns cols [w*64, w*64+64)).
// 2-stage explicit pipeline: kg+1 loads issued before kg's split+MFMA.
// kg loop fully unrolled so stage indices are compile-time (no scratch).
__global__ __launch_bounds__(256) void gemm_kernel(
    const float* __restrict__ X, const u16* __restrict__ Wth,
    const u16* __restrict__ Wtl, u16* __restrict__ H, int Nn)
{
    const int tid = threadIdx.x, m0 = blockIdx.x * 32;
    const int wave = tid >> 6, lane = tid & 63;
    const int quad = lane >> 4, lr = lane & 15;
    const int n0 = wave * 64;

    int rowm[2];
#pragma unroll
    for (int mi = 0; mi < 2; mi++) {
        int r = m0 + mi * 16 + lr;
        rowm[mi] = (r < Nn) ? r : (Nn - 1);          // clamp; stores guarded
    }

    f32x4 acc[2][4] = {};                            // [mi][ni]
    float4 ar[2][2][2];                              // [stage][mi][half]
    bf16x8 bhv[2][4], blv[2][4];                     // [stage][ni]

    // prologue: kg = 0 into stage 0
#pragma unroll
    for (int mi = 0; mi < 2; mi++) {
        const float* xp = X + (size_t)rowm[mi] * 256 + quad * 8;
        ar[0][mi][0] = *(const float4*)xp;
        ar[0][mi][1] = *(const float4*)(xp + 4);
    }
#pragma unroll
    for (int ni = 0; ni < 4; ni++) {
        const size_t bo = (size_t)(n0 + ni * 16 + lr) * 256 + quad * 8;
        bhv[0][ni] = *(const bf16x8*)(Wth + bo);
        blv[0][ni] = *(const bf16x8*)(Wtl + bo);
    }

#pragma unroll
    for (int kg = 0; kg < 8; kg++) {
        const int st = kg & 1, ns = st ^ 1;
        if (kg < 7) {                                // prefetch kg+1
            const int ko = (kg + 1) * 32 + quad * 8;
#pragma unroll
            for (int mi = 0; mi < 2; mi++) {
                const float* xp = X + (size_t)rowm[mi] * 256 + ko;
                ar[ns][mi][0] = *(const float4*)xp;
                ar[ns][mi][1] = *(const float4*)(xp + 4);
            }
#pragma unroll
            for (int ni = 0; ni < 4; ni++) {
                const size_t bo = (size_t)(n0 + ni * 16 + lr) * 256 + ko;
                bhv[ns][ni] = *(const bf16x8*)(Wth + bo);
                blv[ns][ni] = *(const bf16x8*)(Wtl + bo);
            }
        }
        // split current A stage to hi/lo bf16
        bf16x8 ah[2], al[2];
#pragma unroll
        for (int mi = 0; mi < 2; mi++) {
            const float fv[8] = {ar[st][mi][0].x, ar[st][mi][0].y,
                                 ar[st][mi][0].z, ar[st][mi][0].w,
                                 ar[st][mi][1].x, ar[st][mi][1].y,
                                 ar[st][mi][1].z, ar[st][mi][1].w};
            u16x8 hb, lb;
#pragma unroll
            for (int j = 0; j < 8; j++) {
                u16 th, tl;
                split2(fv[j], th, tl);
                hb[j] = th;
                lb[j] = tl;
            }
            ah[mi] = __builtin_bit_cast(bf16x8, hb);
            al[mi] = __builtin_bit_cast(bf16x8, lb);
        }
#pragma unroll
        for (int ni = 0; ni < 4; ni++)
#pragma unroll
            for (int mi = 0; mi < 2; mi++) {
                acc[mi][ni] = __builtin_amdgcn_mfma_f32_16x16x32_bf16(
                    ah[mi], bhv[st][ni], acc[mi][ni], 0, 0, 0);
                acc[mi][ni] = __builtin_amdgcn_mfma_f32_16x16x32_bf16(
                    ah[mi], blv[st][ni], acc[mi][ni], 0, 0, 0);
                acc[mi][ni] = __builtin_amdgcn_mfma_f32_16x16x32_bf16(
                    al[mi], bhv[st][ni], acc[mi][ni], 0, 0, 0);
            }
    }
    // C/D: col = lane&15 (lr), row = quad*4 + r
#pragma unroll
    for (int mi = 0; mi < 2; mi++)
#pragma unroll
        for (int ni = 0; ni < 4; ni++) {
            int col = n0 + ni * 16 + lr;
#pragma unroll
            for (int r = 0; r < 4; r++) {
                int row = m0 + mi * 16 + quad * 4 + r;
                if (row < Nn) H[(size_t)row * 256 + col] = f2bf(acc[mi][ni][r]);
            }
        }
}

// ---------------- CSR build ------------------------------------------------
__global__ void hist_kernel(const int* __restrict__ dst, int* __restrict__ deg,
                            int E, int Nn)
{
    for (int e = blockIdx.x * blockDim.x + threadIdx.x; e < E;
         e += gridDim.x * blockDim.x) {
        int i = dst[e];
        i = ((unsigned)i < (unsigned)Nn) ? i : 0;
        atomicAdd(&deg[i], 1);
    }
}

__global__ __launch_bounds__(1024) void scanA_kernel(
    const int* __restrict__ deg, int* __restrict__ offs,
    int* __restrict__ bsum, int Nn)
{
    __shared__ int wsum[16];
    const int t = threadIdx.x, wv = t >> 6, ln = t & 63;
    const int idx = blockIdx.x * 1024 + t;
    int v = (idx < Nn) ? deg[idx] : 0;
    int s = v;
#pragma unroll
    for (int o = 1; o < 64; o <<= 1) {
        int u = __shfl_up(s, o, 64);
        if (ln >= o) s += u;
    }
    if (ln == 63) wsum[wv] = s;
    __syncthreads();
    if (t == 0) {
        int run = 0;
#pragma unroll
        for (int w = 0; w < 16; w++) { int x = wsum[w]; wsum[w] = run; run += x; }
        bsum[blockIdx.x] = run;
    }
    __syncthreads();
    if (idx < Nn) offs[idx] = wsum[wv] + s - v;      // block-local exclusive
}

__global__ void scanB_kernel(int* __restrict__ bsum, int nb)  // 1 wave
{
    const int ln = threadIdx.x;
    int v = (ln < nb) ? bsum[ln] : 0;
    int s = v;
#pragma unroll
    for (int o = 1; o < 64; o <<= 1) {
        int u = __shfl_up(s, o, 64);
        if (ln >= o) s += u;
    }
    if (ln < nb) bsum[ln] = s - v;                   // exclusive
}

__global__ __launch_bounds__(1024) void scanC_kernel(
    int* __restrict__ offs, const int* __restrict__ bsum,
    int* __restrict__ cur, int Nn)
{
    const int idx = blockIdx.x * 1024 + threadIdx.x;
    if (idx < Nn) {
        int o = offs[idx] + bsum[blockIdx.x];
        offs[idx] = o;
        cur[idx] = o;
    }
}

__global__ void scatter_kernel(
    const int* __restrict__ src, const int* __restrict__ dst,
    int* __restrict__ cur, int* __restrict__ csr_src, int E, int Nn)
{
    for (int e = blockIdx.x * blockDim.x + threadIdx.x; e < E;
         e += gridDim.x * blockDim.x) {
        int j = src[e], i = dst[e];
        j = ((unsigned)j < (unsigned)Nn) ? j : 0;
        i = ((unsigned)i < (unsigned)Nn) ? i : 0;
        int pos = atomicAdd(&cur[i], 1);
        if ((unsigned)pos < (unsigned)E) csr_src[pos] = j;
    }
}

// ---------------- gather: 1 wave/node, 4 ch/thread, unroll x4 --------------
__global__ __launch_bounds__(256) void gather_kernel(
    const u16* __restrict__ H, const int* __restrict__ offs,
    const int* __restrict__ deg, const int* __restrict__ csr_src,
    const float* __restrict__ a_src, const float* __restrict__ a_dst,
    const float* __restrict__ bias, const float* __restrict__ prelu,
    float* __restrict__ out, int Nn)
{
    const int wave = threadIdx.x >> 6, lane = threadIdx.x & 63;
    const int node = blockIdx.x * 4 + wave;
    if (node >= Nn) return;
    const int head = lane >> 4;
    const int c = lane * 4;                          // 4 channels / thread

    const float adv = a_dst[node * 4 + head];
    float acc0, acc1, acc2, acc3, sumw;
    {   // self loop
        float ws = wexp(a_src[node * 4 + head] + adv);
        uint2 hv = *(const uint2*)(H + (size_t)node * 256 + c);
        acc0 = ws * bf2f((u16)hv.x);
        acc1 = ws * bf2f((u16)(hv.x >> 16));
        acc2 = ws * bf2f((u16)hv.y);
        acc3 = ws * bf2f((u16)(hv.y >> 16));
        sumw = ws;
    }
    const int start = offs[node];
    const int d = deg[node];
    int k = 0;
    for (; k + 4 <= d; k += 4) {
        const int j0 = csr_src[start + k];
        const int j1 = csr_src[start + k + 1];
        const int j2 = csr_src[start + k + 2];
        const int j3 = csr_src[start + k + 3];
        const uint2 h0 = *(const uint2*)(H + (size_t)j0 * 256 + c);
        const uint2 h1 = *(const uint2*)(H + (size_t)j1 * 256 + c);
        const uint2 h2 = *(const uint2*)(H + (size_t)j2 * 256 + c);
        const uint2 h3 = *(const uint2*)(H + (size_t)j3 * 256 + c);
        const float w0 = wexp(a_src[j0 * 4 + head] + adv);
        const float w1 = wexp(a_src[j1 * 4 + head] + adv);
        const float w2 = wexp(a_src[j2 * 4 + head] + adv);
        const float w3 = wexp(a_src[j3 * 4 + head] + adv);
        acc0 += w0 * bf2f((u16)h0.x) + w1 * bf2f((u16)h1.x)
              + w2 * bf2f((u16)h2.x) + w3 * bf2f((u16)h3.x);
        acc1 += w0 * bf2f((u16)(h0.x >> 16)) + w1 * bf2f((u16)(h1.x >> 16))
              + w2 * bf2f((u16)(h2.x >> 16)) + w3 * bf2f((u16)(h3.x >> 16));
        acc2 += w0 * bf2f((u16)h0.y) + w1 * bf2f((u16)h1.y)
              + w2 * bf2f((u16)h2.y) + w3 * bf2f((u16)h3.y);
        acc3 += w0 * bf2f((u16)(h0.y >> 16)) + w1 * bf2f((u16)(h1.y >> 16))
              + w2 * bf2f((u16)(h2.y >> 16)) + w3 * bf2f((u16)(h3.y >> 16));
        sumw += (w0 + w1) + (w2 + w3);
    }
    for (; k < d; k++) {
        const int j = csr_src[start + k];
        const uint2 hv = *(const uint2*)(H + (size_t)j * 256 + c);
        const float w = wexp(a_src[j * 4 + head] + adv);
        acc0 += w * bf2f((u16)hv.x);
        acc1 += w * bf2f((u16)(hv.x >> 16));
        acc2 += w * bf2f((u16)hv.y);
        acc3 += w * bf2f((u16)(hv.y >> 16));
        sumw += w;
    }
    const float inv = 1.f / (sumw + 1e-16f);
    const float pa = prelu[0];
    const float4 bv = *(const float4*)(bias + c);
    float4 ov;
    ov.x = acc0 * inv + bv.x; ov.x = ov.x >= 0.f ? ov.x : pa * ov.x;
    ov.y = acc1 * inv + bv.y; ov.y = ov.y >= 0.f ? ov.y : pa * ov.y;
    ov.z = acc2 * inv + bv.z; ov.z = ov.z >= 0.f ? ov.z : pa * ov.z;
    ov.w = acc3 * inv + bv.w; ov.w = ov.w >= 0.f ? ov.w : pa * ov.w;
    *(float4*)(out + (size_t)node * 256 + c) = ov;
}

// ---------------------------------------------------------------------------
extern "C" void kernel_launch(void* const* d_in, const int* in_sizes, int n_in,
                              void* d_out, int out_size, void* d_ws, size_t ws_size,
                              hipStream_t stream)
{
    const float* X    = (const float*)d_in[0];
    const int*   EI   = (const int*)d_in[1];
    const float* W    = (const float*)d_in[2];
    const float* attS = (const float*)d_in[3];
    const float* attD = (const float*)d_in[4];
    const float* bias = (const float*)d_in[5];
    const float* pa   = (const float*)d_in[6];

    const int Nn = in_sizes[0] / 256;   // 50000
    const int E  = in_sizes[1] / 2;     // 800000
    const int* esrc = EI;
    const int* edst = EI + E;
    const int nbScan = (Nn + 1023) / 1024;   // 49 <= 64

    // workspace carve (~31 MB), all segments 16B-aligned
    char* p = (char*)d_ws;
    u16*   H       = (u16*)p;   p += (size_t)Nn * 256 * 2;
    float* a_src   = (float*)p; p += (size_t)Nn * 4 * 4;
    float* a_dst   = (float*)p; p += (size_t)Nn * 4 * 4;
    float* us      = (float*)p; p += 1024 * 4;
    float* ud      = (float*)p; p += 1024 * 4;
    u16*   Wth     = (u16*)p;   p += 256 * 256 * 2;
    u16*   Wtl     = (u16*)p;   p += 256 * 256 * 2;
    int*   deg     = (int*)p;   p += (size_t)Nn * 4;
    int*   offs    = (int*)p;   p += (size_t)Nn * 4;
    int*   cur     = (int*)p;   p += (size_t)Nn * 4;
    int*   bsum    = (int*)p;   p += 64 * 4;
    int*   csr_src = (int*)p;   p += (size_t)E * 4;

    (void)hipMemsetAsync(deg, 0, (size_t)Nn * 4, stream);

    prep_kernel<<<1, 256, 0, stream>>>(W, attS, attD, us, ud);
    trans_kernel<<<256, 256, 0, stream>>>(W, Wth, Wtl);
    att_kernel<<<(Nn + 3) / 4, 256, 0, stream>>>(X, us, ud, a_src, a_dst, Nn);
    gemm_kernel<<<(Nn + 31) / 32, 256, 0, stream>>>(X, Wth, Wtl, H, Nn);
    hist_kernel<<<2048, 256, 0, stream>>>(edst, deg, E, Nn);
    scanA_kernel<<<nbScan, 1024, 0, stream>>>(deg, offs, bsum, Nn);
    scanB_kernel<<<1, 64, 0, stream>>>(bsum, nbScan);
    scanC_kernel<<<nbScan, 1024, 0, stream>>>(offs, bsum, cur, Nn);
    scatter_kernel<<<2048, 256, 0, stream>>>(esrc, edst, cur, csr_src, E, Nn);
    gather_kernel<<<(Nn + 3) / 4, 256, 0, stream>>>(H, offs, deg, csr_src,
                                                    a_src, a_dst, bias, pa,
                                                    (float*)d_out, Nn);
}

// Round 7
// 340.351 us; speedup vs baseline: 1.1255x; 1.1255x over previous
//
#include <hip/hip_runtime.h>
#include <stdint.h>

// GAT forward, MI355X. FP32 in/out; edge_index int32. N=50000, E=800000,
// HEADS=4, C=64 (HC=256).
// Pipeline:
//   prep:  us/ud[4][256] = W @ att (fp32-exact logits path)
//   trans: Wfh/Wfl = trunc-split bf16 of W^T in MFMA-FRAGMENT-MAJOR order
//          (R7: every B load = coalesced 1024B wave load; R6's 512B-stride
//          layout made each load a 16-cache-line gather -> latency bound)
//   att:   a_src/a_dst[i][h] = x[i]·us/ud  (fp32 exact)
//   gemm:  H = x@W via split-bf16 MFMA (3 terms, err ~2^-17), H stored bf16.
//          R7: 64x256 block, X-tile staged in padded LDS (A frag = one
//          ds_read_b128), B double-buffered from L2. R5/R6 had MfmaUtil 9%,
//          all loads 16-line gathers, VGPR 56 = collapsed pipeline.
//   hist/scanA+B+C/scatter: CSR of edges grouped by destination (src idx only)
//   gather: out = (w_self*h_i + sum_j w_j*h_j)/(sum w) + bias, PReLU
//           w computed inline from a_src[j]+a_dst[i] (leaky+exp), unroll x4.
// Softmax shift omitted: logits fp32-exact, |e|<~12 -> exp<=1.6e5, fp32-safe;
// softmax is shift-invariant. Dominant output error = bf16 H storage (~0.016
// absmax vs 0.0575 threshold, verified rounds 3/5/6).

using u16 = unsigned short;
typedef float f32x4 __attribute__((ext_vector_type(4)));
typedef __bf16 bf16x8 __attribute__((ext_vector_type(8)));
typedef u16 u16x8 __attribute__((ext_vector_type(8)));

#define NEG 0.2f
#define APAD 264   // 256 + 8 u16 pad: row stride 528 B -> 2-way LDS aliasing (free)

__device__ __forceinline__ float bf2f(u16 u) {
    union { uint32_t i; float f; } v; v.i = ((uint32_t)u) << 16; return v.f;
}
__device__ __forceinline__ u16 f2bf(float f) {          // RNE
    union { float f; uint32_t i; } v; v.f = f;
    uint32_t r = v.i + 0x7FFFu + ((v.i >> 16) & 1u);
    return (u16)(r >> 16);
}
// trunc split: f ~= hi + lo with |err| ~ 2^-17 |f|
__device__ __forceinline__ void split2(float f, u16& h, u16& l) {
    union { float f; uint32_t i; } v; v.f = f;
    h = (u16)(v.i >> 16);
    float r = f - bf2f(h);
    union { float f; uint32_t i; } w; w.f = r;
    l = (u16)(w.i >> 16);
}
__device__ __forceinline__ float wexp(float e) {
    e = e >= 0.f ? e : NEG * e;
    return __expf(e);
}

// ---------------- prep: us[h][k] = sum_c W[k][h*64+c]*attS[h][c] -----------
__global__ __launch_bounds__(256) void prep_kernel(
    const float* __restrict__ W, const float* __restrict__ attS,
    const float* __restrict__ attD, float* __restrict__ us, float* __restrict__ ud)
{
    const int k = threadIdx.x;
#pragma unroll
    for (int hh = 0; hh < 4; hh++) {
        float ss = 0.f, sd = 0.f;
        for (int c = 0; c < 64; c++) {
            float w = W[k * 256 + hh * 64 + c];
            ss += w * attS[hh * 64 + c];
            sd += w * attD[hh * 64 + c];
        }
        us[hh * 256 + k] = ss;
        ud[hh * 256 + k] = sd;
    }
}

// ---------------- trans: fragment-major split W^T --------------------------
// Wf[((kg*16+nb)*64 + lane)*8 + j] = split(W[(kg*32+(lane>>4)*8+j)*256 + nb*16+(lane&15)])
// so a wave's B-fragment load for (kg, nb) is one coalesced 1024B read.
__global__ __launch_bounds__(256) void trans_kernel(
    const float* __restrict__ W, u16* __restrict__ Wfh, u16* __restrict__ Wfl)
{
    const int f = blockIdx.x * 4 + (threadIdx.x >> 6);   // 128 frags = kg*16+nb
    const int l = threadIdx.x & 63;
    const int kg = f >> 4, nb = f & 15;
    const int n = nb * 16 + (l & 15);
    const int kb = kg * 32 + (l >> 4) * 8;
    u16x8 hv, lv;
#pragma unroll
    for (int j = 0; j < 8; j++) {
        u16 th, tl;
        split2(W[(size_t)(kb + j) * 256 + n], th, tl);
        hv[j] = th;
        lv[j] = tl;
    }
    *(u16x8*)(Wfh + ((size_t)f * 64 + l) * 8) = hv;
    *(u16x8*)(Wfl + ((size_t)f * 64 + l) * 8) = lv;
}

// ---------------- att: a_src[i][h] = x[i]·us[h] (fp32 exact) ---------------
__global__ __launch_bounds__(256) void att_kernel(
    const float* __restrict__ X, const float* __restrict__ usg,
    const float* __restrict__ udg, float* __restrict__ a_src,
    float* __restrict__ a_dst, int Nn)
{
    __shared__ float us[1024], ud[1024];
    const int tid = threadIdx.x;
#pragma unroll
    for (int i = 0; i < 4; i++) {
        us[i * 256 + tid] = usg[i * 256 + tid];
        ud[i * 256 + tid] = udg[i * 256 + tid];
    }
    __syncthreads();
    const int wave = tid >> 6, lane = tid & 63;
    const int node = blockIdx.x * 4 + wave;
    if (node >= Nn) return;
    const float4 xv = *(const float4*)(X + (size_t)node * 256 + lane * 4);
    float ps[4], pd[4];
#pragma unroll
    for (int hh = 0; hh < 4; hh++) {
        int b = hh * 256 + lane * 4;
        ps[hh] = xv.x * us[b] + xv.y * us[b + 1] + xv.z * us[b + 2] + xv.w * us[b + 3];
        pd[hh] = xv.x * ud[b] + xv.y * ud[b + 1] + xv.z * ud[b + 2] + xv.w * ud[b + 3];
    }
#pragma unroll
    for (int off = 32; off > 0; off >>= 1)
#pragma unroll
        for (int hh = 0; hh < 4; hh++) {
            ps[hh] += __shfl_down(ps[hh], off, 64);
            pd[hh] += __shfl_down(pd[hh], off, 64);
        }
    if (lane == 0)
#pragma unroll
        for (int hh = 0; hh < 4; hh++) {
            a_src[node * 4 + hh] = ps[hh];
            a_dst[node * 4 + hh] = pd[hh];
        }
}

// ---------------- GEMM: H = x @ W, LDS-staged A, frag-major B --------------
// Block 64 rows x 256 cols, 4 waves; wave w owns cols [w*64, w*64+64).
// Stage: 64x256 fp32 X-tile -> split hi/lo bf16 into padded LDS (coalesced
// float4 global reads). Compute: 8 kg steps, A = ds_read_b128, B = coalesced
// 16B global from Wfh/Wfl (L2-resident, double-buffered), 48 MFMA/kg.
__global__ __launch_bounds__(256, 2) void gemm_kernel(
    const float* __restrict__ X, const u16* __restrict__ Wfh,
    const u16* __restrict__ Wfl, u16* __restrict__ H, int Nn)
{
    __shared__ u16 Ah[64 * APAD];
    __shared__ u16 Al[64 * APAD];
    const int tid = threadIdx.x, m0 = blockIdx.x * 64;
    const int wave = tid >> 6, lane = tid & 63;
    const int quad = lane >> 4, lr = lane & 15;

    // ---- stage X tile (64 rows x 256 cols) as split bf16 ----
#pragma unroll
    for (int i = 0; i < 16; i++) {
        const int f = i * 256 + tid;            // float4 index in tile
        const int row = f >> 6;                 // 64 float4 per row
        const int c4 = (f & 63) * 4;
        int grow = m0 + row;
        if (grow >= Nn) grow = Nn - 1;          // clamp; stores guarded
        const float4 v = *(const float4*)(X + (size_t)grow * 256 + c4);
        u16 h0, l0, h1, l1, h2, l2, h3, l3;
        split2(v.x, h0, l0); split2(v.y, h1, l1);
        split2(v.z, h2, l2); split2(v.w, h3, l3);
        uint2 hp, lp;
        hp.x = (uint32_t)h0 | ((uint32_t)h1 << 16);
        hp.y = (uint32_t)h2 | ((uint32_t)h3 << 16);
        lp.x = (uint32_t)l0 | ((uint32_t)l1 << 16);
        lp.y = (uint32_t)l2 | ((uint32_t)l3 << 16);
        *(uint2*)(Ah + row * APAD + c4) = hp;   // 8B aligned
        *(uint2*)(Al + row * APAD + c4) = lp;
    }
    __syncthreads();

    f32x4 acc[4][4] = {};                       // [mi][ni]
    bf16x8 bh[2][4], bl[2][4];                  // B double buffer

    // prologue: kg=0 B frags (frag id = kg*16 + wave*4 + ni)
#pragma unroll
    for (int ni = 0; ni < 4; ni++) {
        const size_t o = ((size_t)(wave * 4 + ni) * 64 + lane) * 8;
        bh[0][ni] = *(const bf16x8*)(Wfh + o);
        bl[0][ni] = *(const bf16x8*)(Wfl + o);
    }

#pragma unroll
    for (int kg = 0; kg < 8; kg++) {
        const int st = kg & 1, ns = st ^ 1;
        if (kg < 7) {                           // prefetch kg+1 B
#pragma unroll
            for (int ni = 0; ni < 4; ni++) {
                const size_t o = ((size_t)((kg + 1) * 16 + wave * 4 + ni) * 64 + lane) * 8;
                bh[ns][ni] = *(const bf16x8*)(Wfh + o);
                bl[ns][ni] = *(const bf16x8*)(Wfl + o);
            }
        }
        bf16x8 ah[4], al[4];
#pragma unroll
        for (int mi = 0; mi < 4; mi++) {
            const int o = (mi * 16 + lr) * APAD + kg * 32 + quad * 8;
            ah[mi] = *(const bf16x8*)(Ah + o);  // ds_read_b128
            al[mi] = *(const bf16x8*)(Al + o);
        }
#pragma unroll
        for (int ni = 0; ni < 4; ni++)
#pragma unroll
            for (int mi = 0; mi < 4; mi++) {
                acc[mi][ni] = __builtin_amdgcn_mfma_f32_16x16x32_bf16(
                    ah[mi], bh[st][ni], acc[mi][ni], 0, 0, 0);
                acc[mi][ni] = __builtin_amdgcn_mfma_f32_16x16x32_bf16(
                    ah[mi], bl[st][ni], acc[mi][ni], 0, 0, 0);
                acc[mi][ni] = __builtin_amdgcn_mfma_f32_16x16x32_bf16(
                    al[mi], bh[st][ni], acc[mi][ni], 0, 0, 0);
            }
    }

    // C/D: col = lane&15 (lr), row = quad*4 + r
    const int n0 = wave * 64;
#pragma unroll
    for (int mi = 0; mi < 4; mi++)
#pragma unroll
        for (int ni = 0; ni < 4; ni++) {
            int col = n0 + ni * 16 + lr;
#pragma unroll
            for (int r = 0; r < 4; r++) {
                int row = m0 + mi * 16 + quad * 4 + r;
                if (row < Nn) H[(size_t)row * 256 + col] = f2bf(acc[mi][ni][r]);
            }
        }
}

// ---------------- CSR build ------------------------------------------------
__global__ void hist_kernel(const int* __restrict__ dst, int* __restrict__ deg,
                            int E, int Nn)
{
    for (int e = blockIdx.x * blockDim.x + threadIdx.x; e < E;
         e += gridDim.x * blockDim.x) {
        int i = dst[e];
        i = ((unsigned)i < (unsigned)Nn) ? i : 0;
        atomicAdd(&deg[i], 1);
    }
}

__global__ __launch_bounds__(1024) void scanA_kernel(
    const int* __restrict__ deg, int* __restrict__ offs,
    int* __restrict__ bsum, int Nn)
{
    __shared__ int wsum[16];
    const int t = threadIdx.x, wv = t >> 6, ln = t & 63;
    const int idx = blockIdx.x * 1024 + t;
    int v = (idx < Nn) ? deg[idx] : 0;
    int s = v;
#pragma unroll
    for (int o = 1; o < 64; o <<= 1) {
        int u = __shfl_up(s, o, 64);
        if (ln >= o) s += u;
    }
    if (ln == 63) wsum[wv] = s;
    __syncthreads();
    if (t == 0) {
        int run = 0;
#pragma unroll
        for (int w = 0; w < 16; w++) { int x = wsum[w]; wsum[w] = run; run += x; }
        bsum[blockIdx.x] = run;
    }
    __syncthreads();
    if (idx < Nn) offs[idx] = wsum[wv] + s - v;      // block-local exclusive
}

__global__ void scanB_kernel(int* __restrict__ bsum, int nb)  // 1 wave
{
    const int ln = threadIdx.x;
    int v = (ln < nb) ? bsum[ln] : 0;
    int s = v;
#pragma unroll
    for (int o = 1; o < 64; o <<= 1) {
        int u = __shfl_up(s, o, 64);
        if (ln >= o) s += u;
    }
    if (ln < nb) bsum[ln] = s - v;                   // exclusive
}

__global__ __launch_bounds__(1024) void scanC_kernel(
    int* __restrict__ offs, const int* __restrict__ bsum,
    int* __restrict__ cur, int Nn)
{
    const int idx = blockIdx.x * 1024 + threadIdx.x;
    if (idx < Nn) {
        int o = offs[idx] + bsum[blockIdx.x];
        offs[idx] = o;
        cur[idx] = o;
    }
}

__global__ void scatter_kernel(
    const int* __restrict__ src, const int* __restrict__ dst,
    int* __restrict__ cur, int* __restrict__ csr_src, int E, int Nn)
{
    for (int e = blockIdx.x * blockDim.x + threadIdx.x; e < E;
         e += gridDim.x * blockDim.x) {
        int j = src[e], i = dst[e];
        j = ((unsigned)j < (unsigned)Nn) ? j : 0;
        i = ((unsigned)i < (unsigned)Nn) ? i : 0;
        int pos = atomicAdd(&cur[i], 1);
        if ((unsigned)pos < (unsigned)E) csr_src[pos] = j;
    }
}

// ---------------- gather: 1 wave/node, 4 ch/thread, unroll x4 --------------
__global__ __launch_bounds__(256) void gather_kernel(
    const u16* __restrict__ H, const int* __restrict__ offs,
    const int* __restrict__ deg, const int* __restrict__ csr_src,
    const float* __restrict__ a_src, const float* __restrict__ a_dst,
    const float* __restrict__ bias, const float* __restrict__ prelu,
    float* __restrict__ out, int Nn)
{
    const int wave = threadIdx.x >> 6, lane = threadIdx.x & 63;
    const int node = blockIdx.x * 4 + wave;
    if (node >= Nn) return;
    const int head = lane >> 4;
    const int c = lane * 4;                          // 4 channels / thread

    const float adv = a_dst[node * 4 + head];
    float acc0, acc1, acc2, acc3, sumw;
    {   // self loop
        float ws = wexp(a_src[node * 4 + head] + adv);
        uint2 hv = *(const uint2*)(H + (size_t)node * 256 + c);
        acc0 = ws * bf2f((u16)hv.x);
        acc1 = ws * bf2f((u16)(hv.x >> 16));
        acc2 = ws * bf2f((u16)hv.y);
        acc3 = ws * bf2f((u16)(hv.y >> 16));
        sumw = ws;
    }
    const int start = offs[node];
    const int d = deg[node];
    int k = 0;
    for (; k + 4 <= d; k += 4) {
        const int j0 = csr_src[start + k];
        const int j1 = csr_src[start + k + 1];
        const int j2 = csr_src[start + k + 2];
        const int j3 = csr_src[start + k + 3];
        const uint2 h0 = *(const uint2*)(H + (size_t)j0 * 256 + c);
        const uint2 h1 = *(const uint2*)(H + (size_t)j1 * 256 + c);
        const uint2 h2 = *(const uint2*)(H + (size_t)j2 * 256 + c);
        const uint2 h3 = *(const uint2*)(H + (size_t)j3 * 256 + c);
        const float w0 = wexp(a_src[j0 * 4 + head] + adv);
        const float w1 = wexp(a_src[j1 * 4 + head] + adv);
        const float w2 = wexp(a_src[j2 * 4 + head] + adv);
        const float w3 = wexp(a_src[j3 * 4 + head] + adv);
        acc0 += w0 * bf2f((u16)h0.x) + w1 * bf2f((u16)h1.x)
              + w2 * bf2f((u16)h2.x) + w3 * bf2f((u16)h3.x);
        acc1 += w0 * bf2f((u16)(h0.x >> 16)) + w1 * bf2f((u16)(h1.x >> 16))
              + w2 * bf2f((u16)(h2.x >> 16)) + w3 * bf2f((u16)(h3.x >> 16));
        acc2 += w0 * bf2f((u16)h0.y) + w1 * bf2f((u16)h1.y)
              + w2 * bf2f((u16)h2.y) + w3 * bf2f((u16)h3.y);
        acc3 += w0 * bf2f((u16)(h0.y >> 16)) + w1 * bf2f((u16)(h1.y >> 16))
              + w2 * bf2f((u16)(h2.y >> 16)) + w3 * bf2f((u16)(h3.y >> 16));
        sumw += (w0 + w1) + (w2 + w3);
    }
    for (; k < d; k++) {
        const int j = csr_src[start + k];
        const uint2 hv = *(const uint2*)(H + (size_t)j * 256 + c);
        const float w = wexp(a_src[j * 4 + head] + adv);
        acc0 += w * bf2f((u16)hv.x);
        acc1 += w * bf2f((u16)(hv.x >> 16));
        acc2 += w * bf2f((u16)hv.y);
        acc3 += w * bf2f((u16)(hv.y >> 16));
        sumw += w;
    }
    const float inv = 1.f / (sumw + 1e-16f);
    const float pa = prelu[0];
    const float4 bv = *(const float4*)(bias + c);
    float4 ov;
    ov.x = acc0 * inv + bv.x; ov.x = ov.x >= 0.f ? ov.x : pa * ov.x;
    ov.y = acc1 * inv + bv.y; ov.y = ov.y >= 0.f ? ov.y : pa * ov.y;
    ov.z = acc2 * inv + bv.z; ov.z = ov.z >= 0.f ? ov.z : pa * ov.z;
    ov.w = acc3 * inv + bv.w; ov.w = ov.w >= 0.f ? ov.w : pa * ov.w;
    *(float4*)(out + (size_t)node * 256 + c) = ov;
}

// ---------------------------------------------------------------------------
extern "C" void kernel_launch(void* const* d_in, const int* in_sizes, int n_in,
                              void* d_out, int out_size, void* d_ws, size_t ws_size,
                              hipStream_t stream)
{
    const float* X    = (const float*)d_in[0];
    const int*   EI   = (const int*)d_in[1];
    const float* W    = (const float*)d_in[2];
    const float* attS = (const float*)d_in[3];
    const float* attD = (const float*)d_in[4];
    const float* bias = (const float*)d_in[5];
    const float* pa   = (const float*)d_in[6];

    const int Nn = in_sizes[0] / 256;   // 50000
    const int E  = in_sizes[1] / 2;     // 800000
    const int* esrc = EI;
    const int* edst = EI + E;
    const int nbScan = (Nn + 1023) / 1024;   // 49 <= 64

    // workspace carve (~31 MB), all segments 16B-aligned
    char* p = (char*)d_ws;
    u16*   H       = (u16*)p;   p += (size_t)Nn * 256 * 2;
    float* a_src   = (float*)p; p += (size_t)Nn * 4 * 4;
    float* a_dst   = (float*)p; p += (size_t)Nn * 4 * 4;
    float* us      = (float*)p; p += 1024 * 4;
    float* ud      = (float*)p; p += 1024 * 4;
    u16*   Wfh     = (u16*)p;   p += 256 * 256 * 2;
    u16*   Wfl     = (u16*)p;   p += 256 * 256 * 2;
    int*   deg     = (int*)p;   p += (size_t)Nn * 4;
    int*   offs    = (int*)p;   p += (size_t)Nn * 4;
    int*   cur     = (int*)p;   p += (size_t)Nn * 4;
    int*   bsum    = (int*)p;   p += 64 * 4;
    int*   csr_src = (int*)p;   p += (size_t)E * 4;

    (void)hipMemsetAsync(deg, 0, (size_t)Nn * 4, stream);

    prep_kernel<<<1, 256, 0, stream>>>(W, attS, attD, us, ud);
    trans_kernel<<<32, 256, 0, stream>>>(W, Wfh, Wfl);
    att_kernel<<<(Nn + 3) / 4, 256, 0, stream>>>(X, us, ud, a_src, a_dst, Nn);
    gemm_kernel<<<(Nn + 63) / 64, 256, 0, stream>>>(X, Wfh, Wfl, H, Nn);
    hist_kernel<<<2048, 256, 0, stream>>>(edst, deg, E, Nn);
    scanA_kernel<<<nbScan, 1024, 0, stream>>>(deg, offs, bsum, Nn);
    scanB_kernel<<<1, 64, 0, stream>>>(bsum, nbScan);
    scanC_kernel<<<nbScan, 1024, 0, stream>>>(offs, bsum, cur, Nn);
    scatter_kernel<<<2048, 256, 0, stream>>>(esrc, edst, cur, csr_src, E, Nn);
    gather_kernel<<<(Nn + 3) / 4, 256, 0, stream>>>(H, offs, deg, csr_src,
                                                    a_src, a_dst, bias, pa,
                                                    (float*)d_out, Nn);
}

// Round 8
// 317.556 us; speedup vs baseline: 1.2063x; 1.0718x over previous
//
#include <hip/hip_runtime.h>
#include <stdint.h>

// GAT forward, MI355X. FP32 in/out; edge_index int32. N=50000, E=800000,
// HEADS=4, C=64 (HC=256).
// Pipeline:
//   prep:  us/ud[4][256] = W @ att (fp32-exact logits path). R8: 256 blocks,
//          wave-per-head shfl reduction (was 1 serial block).
//   trans: Wfh/Wfl = trunc-split bf16 of W^T in MFMA-fragment-major order.
//   att:   a_src/a_dst[i][h] = x[i]·us/ud  (fp32 exact)
//   gemm:  H = x@W via split-bf16 MFMA (3 terms, err ~2^-17), H stored bf16.
//          64x256 block, X staged in padded LDS, B dbuf from L2 (R7).
//   hist/scanA/scanC(+spine)/scatter: CSR of edges grouped by destination.
//   gather: out = (w_self*h_i + sum_j w_j*h_j)/(sum w) + bias, PReLU.
//          R8: unroll x8 (8 H-rows in flight; R7 was 4) — FETCH 211MB = 8x H
//          (per-XCD L2 duplication, structural for a random graph), so the
//          floor is ~43 µs at 6 TB/s; R7 ran 69 µs at 48% HBM peak.
// Softmax shift omitted: logits fp32-exact, |e|<~12 -> exp<=1.6e5, fp32-safe;
// softmax is shift-invariant. Dominant output error = bf16 H storage (~0.016
// absmax vs 0.0575 threshold, verified rounds 3/5/6/7).

using u16 = unsigned short;
typedef float f32x4 __attribute__((ext_vector_type(4)));
typedef __bf16 bf16x8 __attribute__((ext_vector_type(8)));
typedef u16 u16x8 __attribute__((ext_vector_type(8)));

#define NEG 0.2f
#define APAD 264   // 256 + 8 u16 pad: row stride 528 B -> 2-way LDS aliasing (free)

__device__ __forceinline__ float bf2f(u16 u) {
    union { uint32_t i; float f; } v; v.i = ((uint32_t)u) << 16; return v.f;
}
__device__ __forceinline__ u16 f2bf(float f) {          // RNE
    union { float f; uint32_t i; } v; v.f = f;
    uint32_t r = v.i + 0x7FFFu + ((v.i >> 16) & 1u);
    return (u16)(r >> 16);
}
// trunc split: f ~= hi + lo with |err| ~ 2^-17 |f|
__device__ __forceinline__ void split2(float f, u16& h, u16& l) {
    union { float f; uint32_t i; } v; v.f = f;
    h = (u16)(v.i >> 16);
    float r = f - bf2f(h);
    union { float f; uint32_t i; } w; w.f = r;
    l = (u16)(w.i >> 16);
}
__device__ __forceinline__ float wexp(float e) {
    e = e >= 0.f ? e : NEG * e;
    return __expf(e);
}

// ---------------- prep: us[h][k] = sum_c W[k][h*64+c]*attS[h][c] -----------
// R8: block per k, wave per head, coalesced row read + shfl-tree reduce.
__global__ __launch_bounds__(256) void prep_kernel(
    const float* __restrict__ W, const float* __restrict__ attS,
    const float* __restrict__ attD, float* __restrict__ us, float* __restrict__ ud)
{
    const int k = blockIdx.x;                       // 0..255
    const int h = threadIdx.x >> 6, ln = threadIdx.x & 63;
    const float w = W[k * 256 + h * 64 + ln];
    float ss = w * attS[h * 64 + ln];
    float sd = w * attD[h * 64 + ln];
#pragma unroll
    for (int off = 32; off > 0; off >>= 1) {
        ss += __shfl_down(ss, off, 64);
        sd += __shfl_down(sd, off, 64);
    }
    if (ln == 0) { us[h * 256 + k] = ss; ud[h * 256 + k] = sd; }
}

// ---------------- trans: fragment-major split W^T --------------------------
// Wf[((kg*16+nb)*64 + lane)*8 + j] = split(W[(kg*32+(lane>>4)*8+j)*256 + nb*16+(lane&15)])
__global__ __launch_bounds__(256) void trans_kernel(
    const float* __restrict__ W, u16* __restrict__ Wfh, u16* __restrict__ Wfl)
{
    const int f = blockIdx.x * 4 + (threadIdx.x >> 6);   // 128 frags = kg*16+nb
    const int l = threadIdx.x & 63;
    const int kg = f >> 4, nb = f & 15;
    const int n = nb * 16 + (l & 15);
    const int kb = kg * 32 + (l >> 4) * 8;
    u16x8 hv, lv;
#pragma unroll
    for (int j = 0; j < 8; j++) {
        u16 th, tl;
        split2(W[(size_t)(kb + j) * 256 + n], th, tl);
        hv[j] = th;
        lv[j] = tl;
    }
    *(u16x8*)(Wfh + ((size_t)f * 64 + l) * 8) = hv;
    *(u16x8*)(Wfl + ((size_t)f * 64 + l) * 8) = lv;
}

// ---------------- att: a_src[i][h] = x[i]·us[h] (fp32 exact) ---------------
__global__ __launch_bounds__(256) void att_kernel(
    const float* __restrict__ X, const float* __restrict__ usg,
    const float* __restrict__ udg, float* __restrict__ a_src,
    float* __restrict__ a_dst, int Nn)
{
    __shared__ float us[1024], ud[1024];
    const int tid = threadIdx.x;
#pragma unroll
    for (int i = 0; i < 4; i++) {
        us[i * 256 + tid] = usg[i * 256 + tid];
        ud[i * 256 + tid] = udg[i * 256 + tid];
    }
    __syncthreads();
    const int wave = tid >> 6, lane = tid & 63;
    const int node = blockIdx.x * 4 + wave;
    if (node >= Nn) return;
    const float4 xv = *(const float4*)(X + (size_t)node * 256 + lane * 4);
    float ps[4], pd[4];
#pragma unroll
    for (int hh = 0; hh < 4; hh++) {
        int b = hh * 256 + lane * 4;
        ps[hh] = xv.x * us[b] + xv.y * us[b + 1] + xv.z * us[b + 2] + xv.w * us[b + 3];
        pd[hh] = xv.x * ud[b] + xv.y * ud[b + 1] + xv.z * ud[b + 2] + xv.w * ud[b + 3];
    }
#pragma unroll
    for (int off = 32; off > 0; off >>= 1)
#pragma unroll
        for (int hh = 0; hh < 4; hh++) {
            ps[hh] += __shfl_down(ps[hh], off, 64);
            pd[hh] += __shfl_down(pd[hh], off, 64);
        }
    if (lane == 0)
#pragma unroll
        for (int hh = 0; hh < 4; hh++) {
            a_src[node * 4 + hh] = ps[hh];
            a_dst[node * 4 + hh] = pd[hh];
        }
}

// ---------------- GEMM: H = x @ W, LDS-staged A, frag-major B --------------
__global__ __launch_bounds__(256, 2) void gemm_kernel(
    const float* __restrict__ X, const u16* __restrict__ Wfh,
    const u16* __restrict__ Wfl, u16* __restrict__ H, int Nn)
{
    __shared__ u16 Ah[64 * APAD];
    __shared__ u16 Al[64 * APAD];
    const int tid = threadIdx.x, m0 = blockIdx.x * 64;
    const int wave = tid >> 6, lane = tid & 63;
    const int quad = lane >> 4, lr = lane & 15;

    // ---- stage X tile (64 rows x 256 cols) as split bf16 ----
#pragma unroll
    for (int i = 0; i < 16; i++) {
        const int f = i * 256 + tid;            // float4 index in tile
        const int row = f >> 6;                 // 64 float4 per row
        const int c4 = (f & 63) * 4;
        int grow = m0 + row;
        if (grow >= Nn) grow = Nn - 1;          // clamp; stores guarded
        const float4 v = *(const float4*)(X + (size_t)grow * 256 + c4);
        u16 h0, l0, h1, l1, h2, l2, h3, l3;
        split2(v.x, h0, l0); split2(v.y, h1, l1);
        split2(v.z, h2, l2); split2(v.w, h3, l3);
        uint2 hp, lp;
        hp.x = (uint32_t)h0 | ((uint32_t)h1 << 16);
        hp.y = (uint32_t)h2 | ((uint32_t)h3 << 16);
        lp.x = (uint32_t)l0 | ((uint32_t)l1 << 16);
        lp.y = (uint32_t)l2 | ((uint32_t)l3 << 16);
        *(uint2*)(Ah + row * APAD + c4) = hp;   // 8B aligned
        *(uint2*)(Al + row * APAD + c4) = lp;
    }
    __syncthreads();

    f32x4 acc[4][4] = {};                       // [mi][ni]
    bf16x8 bh[2][4], bl[2][4];                  // B double buffer

    // prologue: kg=0 B frags (frag id = kg*16 + wave*4 + ni)
#pragma unroll
    for (int ni = 0; ni < 4; ni++) {
        const size_t o = ((size_t)(wave * 4 + ni) * 64 + lane) * 8;
        bh[0][ni] = *(const bf16x8*)(Wfh + o);
        bl[0][ni] = *(const bf16x8*)(Wfl + o);
    }

#pragma unroll
    for (int kg = 0; kg < 8; kg++) {
        const int st = kg & 1, ns = st ^ 1;
        if (kg < 7) {                           // prefetch kg+1 B
#pragma unroll
            for (int ni = 0; ni < 4; ni++) {
                const size_t o = ((size_t)((kg + 1) * 16 + wave * 4 + ni) * 64 + lane) * 8;
                bh[ns][ni] = *(const bf16x8*)(Wfh + o);
                bl[ns][ni] = *(const bf16x8*)(Wfl + o);
            }
        }
        bf16x8 ah[4], al[4];
#pragma unroll
        for (int mi = 0; mi < 4; mi++) {
            const int o = (mi * 16 + lr) * APAD + kg * 32 + quad * 8;
            ah[mi] = *(const bf16x8*)(Ah + o);  // ds_read_b128
            al[mi] = *(const bf16x8*)(Al + o);
        }
#pragma unroll
        for (int ni = 0; ni < 4; ni++)
#pragma unroll
            for (int mi = 0; mi < 4; mi++) {
                acc[mi][ni] = __builtin_amdgcn_mfma_f32_16x16x32_bf16(
                    ah[mi], bh[st][ni], acc[mi][ni], 0, 0, 0);
                acc[mi][ni] = __builtin_amdgcn_mfma_f32_16x16x32_bf16(
                    ah[mi], bl[st][ni], acc[mi][ni], 0, 0, 0);
                acc[mi][ni] = __builtin_amdgcn_mfma_f32_16x16x32_bf16(
                    al[mi], bh[st][ni], acc[mi][ni], 0, 0, 0);
            }
    }

    // C/D: col = lane&15 (lr), row = quad*4 + r
    const int n0 = wave * 64;
#pragma unroll
    for (int mi = 0; mi < 4; mi++)
#pragma unroll
        for (int ni = 0; ni < 4; ni++) {
            int col = n0 + ni * 16 + lr;
#pragma unroll
            for (int r = 0; r < 4; r++) {
                int row = m0 + mi * 16 + quad * 4 + r;
                if (row < Nn) H[(size_t)row * 256 + col] = f2bf(acc[mi][ni][r]);
            }
        }
}

// ---------------- CSR build ------------------------------------------------
__global__ void hist_kernel(const int* __restrict__ dst, int* __restrict__ deg,
                            int E, int Nn)
{
    for (int e = blockIdx.x * blockDim.x + threadIdx.x; e < E;
         e += gridDim.x * blockDim.x) {
        int i = dst[e];
        i = ((unsigned)i < (unsigned)Nn) ? i : 0;
        atomicAdd(&deg[i], 1);
    }
}

__global__ __launch_bounds__(1024) void scanA_kernel(
    const int* __restrict__ deg, int* __restrict__ offs,
    int* __restrict__ bsum, int Nn)
{
    __shared__ int wsum[16];
    const int t = threadIdx.x, wv = t >> 6, ln = t & 63;
    const int idx = blockIdx.x * 1024 + t;
    int v = (idx < Nn) ? deg[idx] : 0;
    int s = v;
#pragma unroll
    for (int o = 1; o < 64; o <<= 1) {
        int u = __shfl_up(s, o, 64);
        if (ln >= o) s += u;
    }
    if (ln == 63) wsum[wv] = s;
    __syncthreads();
    if (t == 0) {
        int run = 0;
#pragma unroll
        for (int w = 0; w < 16; w++) { int x = wsum[w]; wsum[w] = run; run += x; }
        bsum[blockIdx.x] = run;
    }
    __syncthreads();
    if (idx < Nn) offs[idx] = wsum[wv] + s - v;      // block-local exclusive
}

// scanC: adds spine prefix (computed in-block from raw bsum) — scanB folded in.
__global__ __launch_bounds__(1024) void scanC_kernel(
    int* __restrict__ offs, const int* __restrict__ bsum,
    int* __restrict__ cur, int Nn, int nb)
{
    __shared__ int prefix;
    if (threadIdx.x == 0) prefix = 0;
    __syncthreads();
    if (threadIdx.x < 64) {
        const int t = threadIdx.x;
        int v = (t < nb) ? bsum[t] : 0;
        int s = v;
#pragma unroll
        for (int o = 1; o < 64; o <<= 1) {
            int u = __shfl_up(s, o, 64);
            if (t >= o) s += u;
        }
        if ((int)blockIdx.x > 0 && t == (int)blockIdx.x - 1) prefix = s;
    }
    __syncthreads();
    const int idx = blockIdx.x * 1024 + threadIdx.x;
    if (idx < Nn) {
        int o = offs[idx] + prefix;
        offs[idx] = o;
        cur[idx] = o;
    }
}

__global__ void scatter_kernel(
    const int* __restrict__ src, const int* __restrict__ dst,
    int* __restrict__ cur, int* __restrict__ csr_src, int E, int Nn)
{
    for (int e = blockIdx.x * blockDim.x + threadIdx.x; e < E;
         e += gridDim.x * blockDim.x) {
        int j = src[e], i = dst[e];
        j = ((unsigned)j < (unsigned)Nn) ? j : 0;
        i = ((unsigned)i < (unsigned)Nn) ? i : 0;
        int pos = atomicAdd(&cur[i], 1);
        if ((unsigned)pos < (unsigned)E) csr_src[pos] = j;
    }
}

// ---------------- gather: 1 wave/node, 4 ch/thread, unroll x8 --------------
__global__ __launch_bounds__(256) void gather_kernel(
    const u16* __restrict__ H, const int* __restrict__ offs,
    const int* __restrict__ deg, const int* __restrict__ csr_src,
    const float* __restrict__ a_src, const float* __restrict__ a_dst,
    const float* __restrict__ bias, const float* __restrict__ prelu,
    float* __restrict__ out, int Nn)
{
    const int wave = threadIdx.x >> 6, lane = threadIdx.x & 63;
    const int node = blockIdx.x * 4 + wave;
    if (node >= Nn) return;
    const int head = lane >> 4;
    const int c = lane * 4;                          // 4 channels / thread

    const float adv = a_dst[node * 4 + head];
    float acc0, acc1, acc2, acc3, sumw;
    {   // self loop
        float ws = wexp(a_src[node * 4 + head] + adv);
        uint2 hv = *(const uint2*)(H + (size_t)node * 256 + c);
        acc0 = ws * bf2f((u16)hv.x);
        acc1 = ws * bf2f((u16)(hv.x >> 16));
        acc2 = ws * bf2f((u16)hv.y);
        acc3 = ws * bf2f((u16)(hv.y >> 16));
        sumw = ws;
    }
    const int start = offs[node];
    const int d = deg[node];
    int k = 0;
    for (; k + 8 <= d; k += 8) {                     // 8 H-rows in flight
        int j[8]; uint2 hv[8]; float w[8];
#pragma unroll
        for (int q = 0; q < 8; q++) j[q] = csr_src[start + k + q];
#pragma unroll
        for (int q = 0; q < 8; q++) hv[q] = *(const uint2*)(H + (size_t)j[q] * 256 + c);
#pragma unroll
        for (int q = 0; q < 8; q++) w[q] = wexp(a_src[j[q] * 4 + head] + adv);
#pragma unroll
        for (int q = 0; q < 8; q++) {
            acc0 += w[q] * bf2f((u16)hv[q].x);
            acc1 += w[q] * bf2f((u16)(hv[q].x >> 16));
            acc2 += w[q] * bf2f((u16)hv[q].y);
            acc3 += w[q] * bf2f((u16)(hv[q].y >> 16));
            sumw += w[q];
        }
    }
    for (; k + 4 <= d; k += 4) {
        int j[4]; uint2 hv[4]; float w[4];
#pragma unroll
        for (int q = 0; q < 4; q++) j[q] = csr_src[start + k + q];
#pragma unroll
        for (int q = 0; q < 4; q++) hv[q] = *(const uint2*)(H + (size_t)j[q] * 256 + c);
#pragma unroll
        for (int q = 0; q < 4; q++) w[q] = wexp(a_src[j[q] * 4 + head] + adv);
#pragma unroll
        for (int q = 0; q < 4; q++) {
            acc0 += w[q] * bf2f((u16)hv[q].x);
            acc1 += w[q] * bf2f((u16)(hv[q].x >> 16));
            acc2 += w[q] * bf2f((u16)hv[q].y);
            acc3 += w[q] * bf2f((u16)(hv[q].y >> 16));
            sumw += w[q];
        }
    }
    for (; k < d; k++) {
        const int j = csr_src[start + k];
        const uint2 hv = *(const uint2*)(H + (size_t)j * 256 + c);
        const float w = wexp(a_src[j * 4 + head] + adv);
        acc0 += w * bf2f((u16)hv.x);
        acc1 += w * bf2f((u16)(hv.x >> 16));
        acc2 += w * bf2f((u16)hv.y);
        acc3 += w * bf2f((u16)(hv.y >> 16));
        sumw += w;
    }
    const float inv = 1.f / (sumw + 1e-16f);
    const float pa = prelu[0];
    const float4 bv = *(const float4*)(bias + c);
    float4 ov;
    ov.x = acc0 * inv + bv.x; ov.x = ov.x >= 0.f ? ov.x : pa * ov.x;
    ov.y = acc1 * inv + bv.y; ov.y = ov.y >= 0.f ? ov.y : pa * ov.y;
    ov.z = acc2 * inv + bv.z; ov.z = ov.z >= 0.f ? ov.z : pa * ov.z;
    ov.w = acc3 * inv + bv.w; ov.w = ov.w >= 0.f ? ov.w : pa * ov.w;
    *(float4*)(out + (size_t)node * 256 + c) = ov;
}

// ---------------------------------------------------------------------------
extern "C" void kernel_launch(void* const* d_in, const int* in_sizes, int n_in,
                              void* d_out, int out_size, void* d_ws, size_t ws_size,
                              hipStream_t stream)
{
    const float* X    = (const float*)d_in[0];
    const int*   EI   = (const int*)d_in[1];
    const float* W    = (const float*)d_in[2];
    const float* attS = (const float*)d_in[3];
    const float* attD = (const float*)d_in[4];
    const float* bias = (const float*)d_in[5];
    const float* pa   = (const float*)d_in[6];

    const int Nn = in_sizes[0] / 256;   // 50000
    const int E  = in_sizes[1] / 2;     // 800000
    const int* esrc = EI;
    const int* edst = EI + E;
    const int nbScan = (Nn + 1023) / 1024;   // 49 <= 64

    // workspace carve (~31 MB), all segments 16B-aligned
    char* p = (char*)d_ws;
    u16*   H       = (u16*)p;   p += (size_t)Nn * 256 * 2;
    float* a_src   = (float*)p; p += (size_t)Nn * 4 * 4;
    float* a_dst   = (float*)p; p += (size_t)Nn * 4 * 4;
    float* us      = (float*)p; p += 1024 * 4;
    float* ud      = (float*)p; p += 1024 * 4;
    u16*   Wfh     = (u16*)p;   p += 256 * 256 * 2;
    u16*   Wfl     = (u16*)p;   p += 256 * 256 * 2;
    int*   deg     = (int*)p;   p += (size_t)Nn * 4;
    int*   offs    = (int*)p;   p += (size_t)Nn * 4;
    int*   cur     = (int*)p;   p += (size_t)Nn * 4;
    int*   bsum    = (int*)p;   p += 64 * 4;
    int*   csr_src = (int*)p;   p += (size_t)E * 4;

    (void)hipMemsetAsync(deg, 0, (size_t)Nn * 4, stream);

    prep_kernel<<<256, 256, 0, stream>>>(W, attS, attD, us, ud);
    trans_kernel<<<32, 256, 0, stream>>>(W, Wfh, Wfl);
    att_kernel<<<(Nn + 3) / 4, 256, 0, stream>>>(X, us, ud, a_src, a_dst, Nn);
    gemm_kernel<<<(Nn + 63) / 64, 256, 0, stream>>>(X, Wfh, Wfl, H, Nn);
    hist_kernel<<<2048, 256, 0, stream>>>(edst, deg, E, Nn);
    scanA_kernel<<<nbScan, 1024, 0, stream>>>(deg, offs, bsum, Nn);
    scanC_kernel<<<nbScan, 1024, 0, stream>>>(offs, bsum, cur, Nn, nbScan);
    scatter_kernel<<<2048, 256, 0, stream>>>(esrc, edst, cur, csr_src, E, Nn);
    gather_kernel<<<(Nn + 3) / 4, 256, 0, stream>>>(H, offs, deg, csr_src,
                                                    a_src, a_dst, bias, pa,
                                                    (float*)d_out, Nn);
}